// Round 10
// baseline (142.454 us; speedup 1.0000x reference)
//
#include <hip/hip_runtime.h>
#include <cstdint>

typedef __bf16 bf16_t;
typedef bf16_t bf16x4 __attribute__((ext_vector_type(4)));
typedef bf16_t bf16x8 __attribute__((ext_vector_type(8)));
typedef float f32x4 __attribute__((ext_vector_type(4)));
typedef float f32x16 __attribute__((ext_vector_type(16)));

#define GLD_LDS16(g, l)                                                        \
  __builtin_amdgcn_global_load_lds(                                            \
      (const __attribute__((address_space(1))) void*)(g),                      \
      (__attribute__((address_space(3))) void*)(l), 16, 0, 0)

#define LOG2E 1.44269504088896340736f

static __device__ __forceinline__ unsigned short bf16_bits(float f) {
  bf16_t h = (bf16_t)f;
  return __builtin_bit_cast(unsigned short, h);
}

// ---- prep: weight transpose-convert only (x/y cvt folded into qkv) --------
__global__ void prep_kernel(const float* __restrict__ Wq,
                            const float* __restrict__ Wk,
                            const float* __restrict__ Wv,
                            const float* __restrict__ Wo,
                            bf16_t* __restrict__ WqT,
                            bf16_t* __restrict__ WkvT,
                            bf16_t* __restrict__ WoT) {
  __shared__ float tile[32][33];
  int bid = blockIdx.x;
  const float* src; bf16_t* dst; int R, lb;
  if (bid < 1024)      { src = Wq; dst = WqT;                        R = 1024; lb = bid; }
  else if (bid < 3072) { src = Wk; dst = WkvT;                       R = 2048; lb = bid - 1024; }
  else if (bid < 5120) { src = Wv; dst = WkvT + (size_t)1024 * 2048; R = 2048; lb = bid - 3072; }
  else                 { src = Wo; dst = WoT;                        R = 1024; lb = bid - 5120; }
  int c0 = (lb & 31) << 5, r0 = (lb >> 5) << 5;
  int tc = threadIdx.x & 31, tr = threadIdx.x >> 5;  // tr in 0..7
#pragma unroll
  for (int i = 0; i < 4; i++)
    tile[tr + i * 8][tc] = src[(size_t)(r0 + tr + i * 8) * 1024 + c0 + tc];
  __syncthreads();
#pragma unroll
  for (int i = 0; i < 4; i++)
    dst[(size_t)(c0 + tr + i * 8) * R + r0 + tc] = (bf16_t)tile[tc][tr + i * 8];
}

// ---- fused Q-proj + KV-proj, A reg-staged from fp32 (T14), B via gld_lds --
// 128x128x32, 4 waves 2x2, 2-buffer, 1 barrier/K-step. Blocks 0..511: KV
// (long, first); 512..767: Q. A-panel-per-XCD swizzle. LDS slot swizzle:
// slot s holds global slot s ^ ((row>>1)&3) (read with same XOR).
__global__ __launch_bounds__(256, 2) void qkv_kernel(
    const float* __restrict__ xf, const float* __restrict__ yf,
    const bf16_t* __restrict__ WqT, const bf16_t* __restrict__ WkvT,
    bf16_t* __restrict__ Qb, bf16_t* __restrict__ Kb,
    bf16_t* __restrict__ VTb) {
  __shared__ bf16_t As[2][128 * 32];
  __shared__ bf16_t Bs[2][128 * 32];
  const int t = threadIdx.x, w = t >> 6, l = t & 63;
  const int l15 = l & 15, l4 = l >> 4;
  const int wr = w >> 1, wc = w & 1;
  // B staging chunks (gld_lds)
  const int c0 = t, c1 = t + 256;
  const int br0 = c0 >> 2, br1 = c1 >> 2;
  const int bk0 = ((c0 & 3) ^ ((br0 >> 1) & 3)) * 8;
  const int bk1 = ((c1 & 3) ^ ((br1 >> 1) & 3)) * 8;
  // A reg staging: row ar = t>>1, 16 fp32 cols at ac = (t&1)*16
  const int ar = t >> 1, ac = (t & 1) * 16;
  const int sw = (ar >> 1) & 3, sbase = (t & 1) * 2;
  const int woff0 = ar * 32 + ((sbase) ^ sw) * 8;
  const int woff1 = ar * 32 + ((sbase + 1) ^ sw) * 8;
  int offA[4], offB[4];
#pragma unroll
  for (int mi = 0; mi < 4; mi++) {
    int rA = wr * 64 + mi * 16 + l15;
    offA[mi] = rA * 32 + (l4 ^ ((rA >> 1) & 3)) * 8;
    int rB = wc * 64 + mi * 16 + l15;
    offB[mi] = rB * 32 + (l4 ^ ((rB >> 1) & 3)) * 8;
  }
  const bool isQ = blockIdx.x >= 512;
  const int i = isQ ? blockIdx.x - 512 : blockIdx.x;
  const int ybt = (i & 7) * 4 + ((i >> 3) & 3);  // A-panel per XCD
  const int xbt = i >> 5;
  const int m0 = ybt * 128, n0 = xbt * 128;
  const float* A0f = isQ ? xf : yf;
  const float* A1f = isQ ? xf : yf + (size_t)4096 * 1024;
  const bf16_t* BT = isQ ? WqT : WkvT;
  const int Ktot = isQ ? 1024 : 2048;
  const int nkt = Ktot >> 5;
  f32x4 acc[4][4] = {};
  float4 areg[4];

#define LOAD_A(kt)                                                             \
  {                                                                            \
    const int kb = (kt) * 32 + ac;                                             \
    _Pragma("unroll") for (int j = 0; j < 4; j++) {                            \
      int kg = kb + j * 4;                                                     \
      const float* src = (kg < 1024)                                           \
                             ? (A0f + (size_t)(m0 + ar) * 1024 + kg)           \
                             : (A1f + (size_t)(m0 + ar) * 1024 + (kg - 1024)); \
      areg[j] = *(const float4*)src;                                           \
    }                                                                          \
  }
#define STAGE_B(buf, kt)                                                       \
  {                                                                            \
    const int kb = (kt) * 32;                                                  \
    GLD_LDS16(BT + (size_t)(n0 + br0) * Ktot + kb + bk0, Bs[buf] + c0 * 8);    \
    GLD_LDS16(BT + (size_t)(n0 + br1) * Ktot + kb + bk1, Bs[buf] + c1 * 8);    \
  }
#define WRITE_A(buf)                                                           \
  {                                                                            \
    bf16x8 ch0, ch1;                                                           \
    ch0[0] = (bf16_t)areg[0].x; ch0[1] = (bf16_t)areg[0].y;                    \
    ch0[2] = (bf16_t)areg[0].z; ch0[3] = (bf16_t)areg[0].w;                    \
    ch0[4] = (bf16_t)areg[1].x; ch0[5] = (bf16_t)areg[1].y;                    \
    ch0[6] = (bf16_t)areg[1].z; ch0[7] = (bf16_t)areg[1].w;                    \
    ch1[0] = (bf16_t)areg[2].x; ch1[1] = (bf16_t)areg[2].y;                    \
    ch1[2] = (bf16_t)areg[2].z; ch1[3] = (bf16_t)areg[2].w;                    \
    ch1[4] = (bf16_t)areg[3].x; ch1[5] = (bf16_t)areg[3].y;                    \
    ch1[6] = (bf16_t)areg[3].z; ch1[7] = (bf16_t)areg[3].w;                    \
    *(bf16x8*)&As[buf][woff0] = ch0;                                           \
    *(bf16x8*)&As[buf][woff1] = ch1;                                           \
  }

  // prologue
  LOAD_A(0);
  STAGE_B(0, 0);
  asm volatile("s_waitcnt vmcnt(0)" ::: "memory");
  WRITE_A(0);
  __syncthreads();
  int cur = 0;
  for (int kt = 0; kt < nkt; ++kt) {
    const bool more = (kt + 1 < nkt);
    if (more) { LOAD_A(kt + 1); STAGE_B(cur ^ 1, kt + 1); }
    bf16x8 af[4], bfr[4];
#pragma unroll
    for (int mi = 0; mi < 4; mi++)
      af[mi] = *(const bf16x8*)&As[cur][offA[mi]];
#pragma unroll
    for (int ni = 0; ni < 4; ni++)
      bfr[ni] = *(const bf16x8*)&Bs[cur][offB[ni]];
#pragma unroll
    for (int mi = 0; mi < 4; mi++)
#pragma unroll
      for (int ni = 0; ni < 4; ni++)
        acc[mi][ni] = __builtin_amdgcn_mfma_f32_16x16x32_bf16(
            af[mi], bfr[ni], acc[mi][ni], 0, 0, 0);
    if (more) {
      asm volatile("s_waitcnt vmcnt(0)" ::: "memory");
      WRITE_A(cur ^ 1);
    }
    __syncthreads();
    cur ^= 1;
  }
#undef LOAD_A
#undef STAGE_B
#undef WRITE_A

#pragma unroll
  for (int mi = 0; mi < 4; mi++) {
#pragma unroll
    for (int ni = 0; ni < 4; ni++) {
      const int rbase = m0 + wr * 64 + mi * 16 + l4 * 4;
      const int col = n0 + wc * 64 + ni * 16 + l15;
      if (isQ) {
#pragma unroll
        for (int rr = 0; rr < 4; rr++)
          Qb[(size_t)(rbase + rr) * 1024 + col] =
              (bf16_t)(acc[mi][ni][rr] * (0.125f * LOG2E));
      } else if (n0 < 1024) {
#pragma unroll
        for (int rr = 0; rr < 4; rr++)
          Kb[(size_t)(rbase + rr) * 1024 + col] = (bf16_t)acc[mi][ni][rr];
      } else {
        union { unsigned short u[4]; uint2 v; } pk;
#pragma unroll
        for (int rr = 0; rr < 4; rr++)
          pk.u[rr] = bf16_bits(acc[mi][ni][rr]);
        *(uint2*)&VTb[(size_t)(col - 1024) * 4096 + rbase] = pk.v;
      }
    }
  }
}

// ---- O-proj: out(fp32) = ctx * WoT^T. 128x64 tiles -> 512 blocks (2/CU) ---
__global__ __launch_bounds__(256, 2) void gemm_o(const bf16_t* __restrict__ A0,
                                                 const bf16_t* __restrict__ BT,
                                                 float* __restrict__ Cp) {
  __shared__ bf16_t As[2][128 * 32];
  __shared__ bf16_t Bs[2][64 * 32];
  const int t = threadIdx.x, w = t >> 6, l = t & 63;
  const int l15 = l & 15, l4 = l >> 4;
  const int wr = w >> 1, wc = w & 1;
  const int c0 = t, c1 = t + 256, c2 = t;
  const int ar0 = c0 >> 2, ar1 = c1 >> 2, br2 = c2 >> 2;
  const int ak0 = ((c0 & 3) ^ ((ar0 >> 1) & 3)) * 8;
  const int ak1 = ((c1 & 3) ^ ((ar1 >> 1) & 3)) * 8;
  const int bk2 = ((c2 & 3) ^ ((br2 >> 1) & 3)) * 8;
  int offA[4], offB[2];
#pragma unroll
  for (int mi = 0; mi < 4; mi++) {
    int rA = wr * 64 + mi * 16 + l15;
    offA[mi] = rA * 32 + (l4 ^ ((rA >> 1) & 3)) * 8;
  }
#pragma unroll
  for (int ni = 0; ni < 2; ni++) {
    int rB = wc * 32 + ni * 16 + l15;
    offB[ni] = rB * 32 + (l4 ^ ((rB >> 1) & 3)) * 8;
  }
  const int i = blockIdx.x;
  const int ybt = (i & 7) * 4 + ((i >> 3) & 3);
  const int xbt = i >> 5;
  const int m0 = ybt * 128, n0 = xbt * 64;
  const int nkt = 32;
  f32x4 acc[4][2] = {};

#define OST(buf, kt)                                                           \
  {                                                                            \
    const int kbase = (kt) * 32;                                               \
    const bf16_t* s0 = A0 + (size_t)(m0 + ar0) * 1024 + kbase + ak0;           \
    GLD_LDS16(s0, As[buf] + c0 * 8);                                           \
    const bf16_t* s1 = A0 + (size_t)(m0 + ar1) * 1024 + kbase + ak1;           \
    GLD_LDS16(s1, As[buf] + c1 * 8);                                           \
    const bf16_t* b0 = BT + (size_t)(n0 + br2) * 1024 + kbase + bk2;           \
    GLD_LDS16(b0, Bs[buf] + c2 * 8);                                           \
  }

  OST(0, 0);
  __syncthreads();
  int cur = 0;
  for (int kt = 0; kt < nkt; ++kt) {
    if (kt + 1 < nkt) OST(cur ^ 1, kt + 1);
    bf16x8 af[4], bfr[2];
#pragma unroll
    for (int mi = 0; mi < 4; mi++)
      af[mi] = *(const bf16x8*)&As[cur][offA[mi]];
#pragma unroll
    for (int ni = 0; ni < 2; ni++)
      bfr[ni] = *(const bf16x8*)&Bs[cur][offB[ni]];
#pragma unroll
    for (int mi = 0; mi < 4; mi++)
#pragma unroll
      for (int ni = 0; ni < 2; ni++)
        acc[mi][ni] = __builtin_amdgcn_mfma_f32_16x16x32_bf16(
            af[mi], bfr[ni], acc[mi][ni], 0, 0, 0);
    __syncthreads();
    cur ^= 1;
  }
#undef OST

#pragma unroll
  for (int mi = 0; mi < 4; mi++) {
#pragma unroll
    for (int ni = 0; ni < 2; ni++) {
      const int rbase = m0 + wr * 64 + mi * 16 + l4 * 4;
      const int col = n0 + wc * 32 + ni * 16 + l15;
#pragma unroll
      for (int rr = 0; rr < 4; rr++)
        Cp[(size_t)(rbase + rr) * 1024 + col] = acc[mi][ni][rr];
    }
  }
}

// ---------------- flash attention, 32x32 MFMA + register-P, KB=128 ---------
__global__ __launch_bounds__(256, 2) void attn_kernel(
    const bf16_t* __restrict__ Q, const bf16_t* __restrict__ K,
    const bf16_t* __restrict__ VT, const float* __restrict__ bias,
    bf16_t* __restrict__ ctx) {
  __shared__ bf16_t Ks[2][128 * 64];  // [key][d], ^(row&7) swizzle
  __shared__ bf16_t Vs[2][64 * 128];  // [d][key], ^((row&7)<<1)
  const int t = threadIdx.x, w = t >> 6, l = t & 63;
  const int l31 = l & 31, hi = l >> 5;
  const int id = blockIdx.x;
  const int bh = id & 63, qt = id >> 6;
  const int b = bh >> 4, h = bh & 15;
  const int q_local = w * 32 + l31;

  bf16x8 qf[4];
  {
    const bf16_t* Qp =
        Q + (size_t)(b * 1024 + qt * 128 + q_local) * 1024 + h * 64 + hi * 8;
#pragma unroll
    for (int ds = 0; ds < 4; ds++) qf[ds] = *(const bf16x8*)&Qp[ds * 16];
  }

#define ATTN_STAGE(buf, kt)                                                    \
  {                                                                            \
    _Pragma("unroll") for (int j = 0; j < 4; j++) {                            \
      int c = t + j * 256;                                                     \
      int rowk = c >> 3, slk = (c & 7) ^ (rowk & 7);                           \
      const bf16_t* srck =                                                     \
          K + (size_t)(b * 1024 + (kt) * 128 + rowk) * 1024 + h * 64 + slk * 8;\
      GLD_LDS16(srck, Ks[buf] + c * 8);                                        \
      int rowv = c >> 4, slv = (c & 15) ^ ((rowv & 7) << 1);                   \
      const bf16_t* srcv =                                                     \
          VT + (size_t)(h * 64 + rowv) * 4096 + b * 1024 + (kt) * 128 +        \
          slv * 8;                                                             \
      GLD_LDS16(srcv, Vs[buf] + c * 8);                                        \
    }                                                                          \
  }

  float mrun = -INFINITY, lrun = 0.f;
  f32x16 cacc[2] = {};

  ATTN_STAGE(0, 0);
  __syncthreads();
  int cur = 0;
  for (int kts = 0; kts < 8; ++kts) {
    if (kts + 1 < 8) ATTN_STAGE(cur ^ 1, kts + 1);

#pragma unroll
    for (int half = 0; half < 2; ++half) {
      f32x16 sacc[2] = {};
#pragma unroll
      for (int ds = 0; ds < 4; ds++) {
#pragma unroll
        for (int kg = 0; kg < 2; kg++) {
          int krow = half * 64 + kg * 32 + l31;
          int eoff = krow * 64 + (((ds * 2 + hi) ^ (krow & 7)) * 8);
          bf16x8 kf = *(const bf16x8*)&Ks[cur][eoff];
          sacc[kg] = __builtin_amdgcn_mfma_f32_32x32x16_bf16(
              kf, qf[ds], sacc[kg], 0, 0, 0);
        }
      }
#pragma unroll
      for (int kg = 0; kg < 2; kg++) {
#pragma unroll
        for (int mm = 0; mm < 4; mm++) {
          f32x4 bb = *(const f32x4*)&bias[b * 1024 + kts * 128 + half * 64 +
                                          kg * 32 + mm * 8 + hi * 4];
#pragma unroll
          for (int rr = 0; rr < 4; rr++)
            sacc[kg][mm * 4 + rr] += (2.0f * LOG2E) * bb[rr];
        }
      }
      float tm = -INFINITY;
#pragma unroll
      for (int kg = 0; kg < 2; kg++)
#pragma unroll
        for (int r = 0; r < 16; r++) tm = fmaxf(tm, sacc[kg][r]);
      tm = fmaxf(tm, __shfl_xor(tm, 32));
      float mnew = fmaxf(mrun, tm);
      float sc = exp2f(mrun - mnew);
      float rsum = 0.f;
#pragma unroll
      for (int kg = 0; kg < 2; kg++)
#pragma unroll
        for (int r = 0; r < 16; r++) {
          float p = exp2f(sacc[kg][r] - mnew);
          sacc[kg][r] = p;
          rsum += p;
        }
      rsum += __shfl_xor(rsum, 32);
      lrun = lrun * sc + rsum;
      mrun = mnew;
#pragma unroll
      for (int dg = 0; dg < 2; dg++)
#pragma unroll
        for (int r = 0; r < 16; r++) cacc[dg][r] *= sc;

      bf16x8 pb[4];
#pragma unroll
      for (int kg = 0; kg < 2; kg++) {
#pragma unroll
        for (int tt = 0; tt < 2; tt++) {
          uint32_t w0A, w1A, w0B, w1B;
          const int mA = 2 * tt, mB = 2 * tt + 1;
          asm("v_cvt_pk_bf16_f32 %0, %1, %2"
              : "=v"(w0A)
              : "v"(sacc[kg][4 * mA + 0]), "v"(sacc[kg][4 * mA + 1]));
          asm("v_cvt_pk_bf16_f32 %0, %1, %2"
              : "=v"(w1A)
              : "v"(sacc[kg][4 * mA + 2]), "v"(sacc[kg][4 * mA + 3]));
          asm("v_cvt_pk_bf16_f32 %0, %1, %2"
              : "=v"(w0B)
              : "v"(sacc[kg][4 * mB + 0]), "v"(sacc[kg][4 * mB + 1]));
          asm("v_cvt_pk_bf16_f32 %0, %1, %2"
              : "=v"(w1B)
              : "v"(sacc[kg][4 * mB + 2]), "v"(sacc[kg][4 * mB + 3]));
          asm("v_permlane32_swap_b32 %0, %1" : "+v"(w0A), "+v"(w0B));
          asm("v_permlane32_swap_b32 %0, %1" : "+v"(w1A), "+v"(w1B));
          union { uint32_t u[4]; bf16x8 v; } pk;
          pk.u[0] = w0A; pk.u[1] = w1A; pk.u[2] = w0B; pk.u[3] = w1B;
          pb[kg * 2 + tt] = pk.v;
        }
      }
#pragma unroll
      for (int dg = 0; dg < 2; dg++) {
#pragma unroll
        for (int k4 = 0; k4 < 4; k4++) {
          int vrow = dg * 32 + l31;
          int s = half * 8 + k4 * 2 + hi;
          int eoff = vrow * 128 + ((s ^ ((vrow & 7) << 1)) * 8);
          bf16x8 vf = *(const bf16x8*)&Vs[cur][eoff];
          cacc[dg] = __builtin_amdgcn_mfma_f32_32x32x16_bf16(
              vf, pb[k4], cacc[dg], 0, 0, 0);
        }
      }
    }
    __syncthreads();
    cur ^= 1;
  }

  bf16_t* T = (bf16_t*)Ks;
  {
    float inv = 1.0f / lrun;
#pragma unroll
    for (int dg = 0; dg < 2; dg++) {
#pragma unroll
      for (int m = 0; m < 4; m++) {
        bf16x4 tv;
#pragma unroll
        for (int rr = 0; rr < 4; rr++)
          tv[rr] = (bf16_t)(cacc[dg][4 * m + rr] * inv);
        int d0 = dg * 32 + m * 8 + hi * 4;
        *(bf16x4*)&T[q_local * 64 + (d0 ^ ((q_local & 7) << 3))] = tv;
      }
    }
  }
  __syncthreads();
#pragma unroll
  for (int c = t; c < 1024; c += 256) {
    int row = c >> 3, col8 = c & 7;
    bf16x8 v = *(const bf16x8*)&T[row * 64 + ((col8 * 8) ^ ((row & 7) << 3))];
    *(bf16x8*)&ctx[(size_t)(b * 1024 + qt * 128 + row) * 1024 + h * 64 +
                   col8 * 8] = v;
  }
#undef ATTN_STAGE
}

extern "C" void kernel_launch(void* const* d_in, const int* in_sizes, int n_in,
                              void* d_out, int out_size, void* d_ws,
                              size_t ws_size, hipStream_t stream) {
  const float* x = (const float*)d_in[0];    // [4,1024,1024]
  const float* y = (const float*)d_in[1];    // [2,4,1024,1024]
  const float* bias = (const float*)d_in[2]; // [4,1,1,1024]
  const float* Wq = (const float*)d_in[3];   // [1024,1024]
  const float* Wk = (const float*)d_in[4];   // [2,1024,1024]
  const float* Wv = (const float*)d_in[5];
  const float* Wo = (const float*)d_in[6];
  float* out = (float*)d_out;                // [4,1024,1024] fp32

  char* ws = (char*)d_ws;
  const size_t MB = 1024 * 1024;
  bf16_t* WqT  = (bf16_t*)(ws + 0 * MB);    // 2MB
  bf16_t* WkvT = (bf16_t*)(ws + 2 * MB);    // 8MB  [2048 n][2048 k]
  bf16_t* WoT  = (bf16_t*)(ws + 10 * MB);   // 2MB
  bf16_t* Qb   = (bf16_t*)(ws + 12 * MB);   // 8MB  (pre-scaled d^-.5*log2e)
  bf16_t* Kb   = (bf16_t*)(ws + 20 * MB);   // 8MB
  bf16_t* VTb  = (bf16_t*)(ws + 28 * MB);   // 8MB  [1024 d][4096 q]
  bf16_t* ctxb = (bf16_t*)(ws + 36 * MB);   // 8MB

  prep_kernel<<<6144, 256, 0, stream>>>(Wq, Wk, Wv, Wo, WqT, WkvT, WoT);
  // KV-proj (blocks 0..511, long, first) + Q-proj (512..767)
  qkv_kernel<<<768, 256, 0, stream>>>(x, y, WqT, WkvT, Qb, Kb, VTb);
  attn_kernel<<<512, 256, 0, stream>>>(Qb, Kb, VTb, bias, ctxb);
  gemm_o<<<512, 256, 0, stream>>>(ctxb, WoT, out);
}

// Round 11
// 131.533 us; speedup vs baseline: 1.0830x; 1.0830x over previous
//
#include <hip/hip_runtime.h>
#include <cstdint>

typedef __bf16 bf16_t;
typedef bf16_t bf16x4 __attribute__((ext_vector_type(4)));
typedef bf16_t bf16x8 __attribute__((ext_vector_type(8)));
typedef float f32x4 __attribute__((ext_vector_type(4)));
typedef float f32x16 __attribute__((ext_vector_type(16)));

#define GLD_LDS16(g, l)                                                        \
  __builtin_amdgcn_global_load_lds(                                            \
      (const __attribute__((address_space(1))) void*)(g),                      \
      (__attribute__((address_space(3))) void*)(l), 16, 0, 0)

#define LOG2E 1.44269504088896340736f

static __device__ __forceinline__ unsigned short bf16_bits(float f) {
  bf16_t h = (bf16_t)f;
  return __builtin_bit_cast(unsigned short, h);
}

// ---- fused prep: fp32->bf16 convert (x,y) + weight transpose-convert ------
__global__ void prep_kernel(const float* __restrict__ x,
                            const float* __restrict__ y,
                            const float* __restrict__ Wq,
                            const float* __restrict__ Wk,
                            const float* __restrict__ Wv,
                            const float* __restrict__ Wo,
                            bf16_t* __restrict__ xb, bf16_t* __restrict__ yb,
                            bf16_t* __restrict__ WqT,
                            bf16_t* __restrict__ WkvT,
                            bf16_t* __restrict__ WoT) {
  __shared__ float tile[32][33];
  int bid = blockIdx.x;
  if (bid < 6144) {
    int i = bid * 256 + threadIdx.x;
    const float* src;
    bf16_t* dst;
    if (i < 524288) { src = x; dst = xb; }
    else            { src = y; dst = yb; i -= 524288; }
    const float4* s = (const float4*)src;
    float4 a = s[i * 2];
    float4 b = s[i * 2 + 1];
    bf16x8 o;
    o[0] = (bf16_t)a.x; o[1] = (bf16_t)a.y; o[2] = (bf16_t)a.z; o[3] = (bf16_t)a.w;
    o[4] = (bf16_t)b.x; o[5] = (bf16_t)b.y; o[6] = (bf16_t)b.z; o[7] = (bf16_t)b.w;
    *(bf16x8*)(dst + (size_t)i * 8) = o;
    return;
  }
  bid -= 6144;
  const float* src; bf16_t* dst; int R, lb;
  if (bid < 1024)      { src = Wq; dst = WqT;                        R = 1024; lb = bid; }
  else if (bid < 3072) { src = Wk; dst = WkvT;                       R = 2048; lb = bid - 1024; }
  else if (bid < 5120) { src = Wv; dst = WkvT + (size_t)1024 * 2048; R = 2048; lb = bid - 3072; }
  else                 { src = Wo; dst = WoT;                        R = 1024; lb = bid - 5120; }
  int c0 = (lb & 31) << 5, r0 = (lb >> 5) << 5;
  int tc = threadIdx.x & 31, tr = threadIdx.x >> 5;  // tr in 0..7
#pragma unroll
  for (int i = 0; i < 4; i++)
    tile[tr + i * 8][tc] = src[(size_t)(r0 + tr + i * 8) * 1024 + c0 + tc];
  __syncthreads();
#pragma unroll
  for (int i = 0; i < 4; i++)
    dst[(size_t)(c0 + tr + i * 8) * R + r0 + tc] = (bf16_t)tile[tc][tr + i * 8];
}

// ============ shared GEMM body pieces (128x128x32, 4 waves 2x2) ============
#define GEMM_STAGE(buf, kt)                                                    \
  {                                                                            \
    const int kbase = (kt) * 32;                                               \
    int kg0 = kbase + ak0;                                                     \
    const bf16_t* s0 = (kg0 < Ksplit)                                          \
                           ? (A0 + (size_t)(m0 + ar0) * 1024 + kg0)            \
                           : (A1 + (size_t)(m0 + ar0) * 1024 + (kg0 - Ksplit));\
    GLD_LDS16(s0, As[buf] + c0 * 8);                                           \
    int kg1 = kbase + ak1;                                                     \
    const bf16_t* s1 = (kg1 < Ksplit)                                          \
                           ? (A0 + (size_t)(m0 + ar1) * 1024 + kg1)            \
                           : (A1 + (size_t)(m0 + ar1) * 1024 + (kg1 - Ksplit));\
    GLD_LDS16(s1, As[buf] + c1 * 8);                                           \
    const bf16_t* b0 = BT + (size_t)(n0 + ar0) * Ktot + kbase + ak0;           \
    GLD_LDS16(b0, Bs[buf] + c0 * 8);                                           \
    const bf16_t* b1 = BT + (size_t)(n0 + ar1) * Ktot + kbase + ak1;           \
    GLD_LDS16(b1, Bs[buf] + c1 * 8);                                           \
  }

#define GEMM_DECLS                                                             \
  const int t = threadIdx.x, w = t >> 6, l = t & 63;                           \
  const int l15 = l & 15, l4 = l >> 4;                                         \
  const int wr = w >> 1, wc = w & 1;                                           \
  const int c0 = t, c1 = t + 256;                                              \
  const int ar0 = c0 >> 2, ar1 = c1 >> 2;                                      \
  const int ak0 = ((c0 & 3) ^ ((ar0 >> 1) & 3)) * 8;                           \
  const int ak1 = ((c1 & 3) ^ ((ar1 >> 1) & 3)) * 8;                           \
  int offA[4], offB[4];                                                        \
  _Pragma("unroll") for (int mi = 0; mi < 4; mi++) {                           \
    int rA = wr * 64 + mi * 16 + l15;                                          \
    offA[mi] = rA * 32 + (l4 ^ ((rA >> 1) & 3)) * 8;                           \
    int rB = wc * 64 + mi * 16 + l15;                                          \
    offB[mi] = rB * 32 + (l4 ^ ((rB >> 1) & 3)) * 8;                           \
  }

#define GEMM_MAINLOOP                                                          \
  GEMM_STAGE(0, 0);                                                            \
  __syncthreads();                                                             \
  int cur = 0;                                                                 \
  for (int kt = 0; kt < nkt; ++kt) {                                           \
    if (kt + 1 < nkt) GEMM_STAGE(cur ^ 1, kt + 1);                             \
    bf16x8 af[4], bfr[4];                                                      \
    _Pragma("unroll") for (int mi = 0; mi < 4; mi++)                           \
        af[mi] = *(const bf16x8*)&As[cur][offA[mi]];                           \
    _Pragma("unroll") for (int ni = 0; ni < 4; ni++)                           \
        bfr[ni] = *(const bf16x8*)&Bs[cur][offB[ni]];                          \
    _Pragma("unroll") for (int mi = 0; mi < 4; mi++)                           \
        _Pragma("unroll") for (int ni = 0; ni < 4; ni++)                       \
            acc[mi][ni] = __builtin_amdgcn_mfma_f32_16x16x32_bf16(             \
                af[mi], bfr[ni], acc[mi][ni], 0, 0, 0);                        \
    __syncthreads();                                                           \
    cur ^= 1;                                                                  \
  }

// ---- fused Q+KV proj: blocks 0..511 -> KV (long, first); 512..767 -> Q ----
__global__ __launch_bounds__(256, 2) void qkv_kernel(
    const bf16_t* __restrict__ xbp, const bf16_t* __restrict__ ybp,
    const bf16_t* __restrict__ WqT, const bf16_t* __restrict__ WkvT,
    bf16_t* __restrict__ Qb, bf16_t* __restrict__ Kb,
    bf16_t* __restrict__ VTb) {
  __shared__ bf16_t As[2][128 * 32];
  __shared__ bf16_t Bs[2][128 * 32];
  GEMM_DECLS
  const bool isQ = blockIdx.x >= 512;
  const int i = isQ ? blockIdx.x - 512 : blockIdx.x;
  const int ybt = (i & 7) * 4 + ((i >> 3) & 3);  // A-panel per XCD
  const int xbt = i >> 5;
  const int m0 = ybt * 128, n0 = xbt * 128;
  const bf16_t* A0 = isQ ? xbp : ybp;
  const bf16_t* A1 = isQ ? xbp : ybp + (size_t)4096 * 1024;
  const int Ksplit = 1024;
  const bf16_t* BT = isQ ? WqT : WkvT;
  const int Ktot = isQ ? 1024 : 2048;
  const int nkt = Ktot >> 5;
  f32x4 acc[4][4] = {};

  GEMM_MAINLOOP

#pragma unroll
  for (int mi = 0; mi < 4; mi++) {
#pragma unroll
    for (int ni = 0; ni < 4; ni++) {
      const int rbase = m0 + wr * 64 + mi * 16 + l4 * 4;
      const int col = n0 + wc * 64 + ni * 16 + l15;
      if (isQ) {
#pragma unroll
        for (int rr = 0; rr < 4; rr++)
          Qb[(size_t)(rbase + rr) * 1024 + col] =
              (bf16_t)(acc[mi][ni][rr] * (0.125f * LOG2E));
      } else if (n0 < 1024) {
#pragma unroll
        for (int rr = 0; rr < 4; rr++)
          Kb[(size_t)(rbase + rr) * 1024 + col] = (bf16_t)acc[mi][ni][rr];
      } else {
        union { unsigned short u[4]; uint2 v; } pk;
#pragma unroll
        for (int rr = 0; rr < 4; rr++)
          pk.u[rr] = bf16_bits(acc[mi][ni][rr]);
        *(uint2*)&VTb[(size_t)(col - 1024) * 4096 + rbase] = pk.v;
      }
    }
  }
}

// ---- O-proj: out(fp32) = ctx * WoT^T. 128x64 tiles -> 512 blocks (2/CU) ---
__global__ __launch_bounds__(256, 2) void gemm_o(const bf16_t* __restrict__ A0,
                                                 const bf16_t* __restrict__ BT,
                                                 float* __restrict__ Cp) {
  __shared__ bf16_t As[2][128 * 32];
  __shared__ bf16_t Bs[2][64 * 32];
  const int t = threadIdx.x, w = t >> 6, l = t & 63;
  const int l15 = l & 15, l4 = l >> 4;
  const int wr = w >> 1, wc = w & 1;
  const int c0 = t, c1 = t + 256, c2 = t;
  const int ar0 = c0 >> 2, ar1 = c1 >> 2, br2 = c2 >> 2;
  const int ak0 = ((c0 & 3) ^ ((ar0 >> 1) & 3)) * 8;
  const int ak1 = ((c1 & 3) ^ ((ar1 >> 1) & 3)) * 8;
  const int bk2 = ((c2 & 3) ^ ((br2 >> 1) & 3)) * 8;
  int offA[4], offB[2];
#pragma unroll
  for (int mi = 0; mi < 4; mi++) {
    int rA = wr * 64 + mi * 16 + l15;
    offA[mi] = rA * 32 + (l4 ^ ((rA >> 1) & 3)) * 8;
  }
#pragma unroll
  for (int ni = 0; ni < 2; ni++) {
    int rB = wc * 32 + ni * 16 + l15;
    offB[ni] = rB * 32 + (l4 ^ ((rB >> 1) & 3)) * 8;
  }
  const int i = blockIdx.x;
  const int ybt = (i & 7) * 4 + ((i >> 3) & 3);
  const int xbt = i >> 5;
  const int m0 = ybt * 128, n0 = xbt * 64;
  const int nkt = 32;
  f32x4 acc[4][2] = {};

#define OST(buf, kt)                                                           \
  {                                                                            \
    const int kbase = (kt) * 32;                                               \
    const bf16_t* s0 = A0 + (size_t)(m0 + ar0) * 1024 + kbase + ak0;           \
    GLD_LDS16(s0, As[buf] + c0 * 8);                                           \
    const bf16_t* s1 = A0 + (size_t)(m0 + ar1) * 1024 + kbase + ak1;           \
    GLD_LDS16(s1, As[buf] + c1 * 8);                                           \
    const bf16_t* b0 = BT + (size_t)(n0 + br2) * 1024 + kbase + bk2;           \
    GLD_LDS16(b0, Bs[buf] + c2 * 8);                                           \
  }

  OST(0, 0);
  __syncthreads();
  int cur = 0;
  for (int kt = 0; kt < nkt; ++kt) {
    if (kt + 1 < nkt) OST(cur ^ 1, kt + 1);
    bf16x8 af[4], bfr[2];
#pragma unroll
    for (int mi = 0; mi < 4; mi++)
      af[mi] = *(const bf16x8*)&As[cur][offA[mi]];
#pragma unroll
    for (int ni = 0; ni < 2; ni++)
      bfr[ni] = *(const bf16x8*)&Bs[cur][offB[ni]];
#pragma unroll
    for (int mi = 0; mi < 4; mi++)
#pragma unroll
      for (int ni = 0; ni < 2; ni++)
        acc[mi][ni] = __builtin_amdgcn_mfma_f32_16x16x32_bf16(
            af[mi], bfr[ni], acc[mi][ni], 0, 0, 0);
    __syncthreads();
    cur ^= 1;
  }
#undef OST

#pragma unroll
  for (int mi = 0; mi < 4; mi++) {
#pragma unroll
    for (int ni = 0; ni < 2; ni++) {
      const int rbase = m0 + wr * 64 + mi * 16 + l4 * 4;
      const int col = n0 + wc * 32 + ni * 16 + l15;
#pragma unroll
      for (int rr = 0; rr < 4; rr++)
        Cp[(size_t)(rbase + rr) * 1024 + col] = acc[mi][ni][rr];
    }
  }
}

// ---------------- flash attention, 32x32 MFMA + register-P, KB=128 ---------
// + T5 setprio around MFMA clusters, T13 defer-max (THR=8, log2 domain).
__global__ __launch_bounds__(256, 2) void attn_kernel(
    const bf16_t* __restrict__ Q, const bf16_t* __restrict__ K,
    const bf16_t* __restrict__ VT, const float* __restrict__ bias,
    bf16_t* __restrict__ ctx) {
  __shared__ bf16_t Ks[2][128 * 64];  // [key][d], ^(row&7) swizzle
  __shared__ bf16_t Vs[2][64 * 128];  // [d][key], ^((row&7)<<1)
  const int t = threadIdx.x, w = t >> 6, l = t & 63;
  const int l31 = l & 31, hi = l >> 5;
  const int id = blockIdx.x;
  const int bh = id & 63, qt = id >> 6;
  const int b = bh >> 4, h = bh & 15;
  const int q_local = w * 32 + l31;

  bf16x8 qf[4];
  {
    const bf16_t* Qp =
        Q + (size_t)(b * 1024 + qt * 128 + q_local) * 1024 + h * 64 + hi * 8;
#pragma unroll
    for (int ds = 0; ds < 4; ds++) qf[ds] = *(const bf16x8*)&Qp[ds * 16];
  }

#define ATTN_STAGE(buf, kt)                                                    \
  {                                                                            \
    _Pragma("unroll") for (int j = 0; j < 4; j++) {                            \
      int c = t + j * 256;                                                     \
      int rowk = c >> 3, slk = (c & 7) ^ (rowk & 7);                           \
      const bf16_t* srck =                                                     \
          K + (size_t)(b * 1024 + (kt) * 128 + rowk) * 1024 + h * 64 + slk * 8;\
      GLD_LDS16(srck, Ks[buf] + c * 8);                                        \
      int rowv = c >> 4, slv = (c & 15) ^ ((rowv & 7) << 1);                   \
      const bf16_t* srcv =                                                     \
          VT + (size_t)(h * 64 + rowv) * 4096 + b * 1024 + (kt) * 128 +        \
          slv * 8;                                                             \
      GLD_LDS16(srcv, Vs[buf] + c * 8);                                        \
    }                                                                          \
  }

  float mrun = -INFINITY, lrun = 0.f;
  f32x16 cacc[2] = {};

  ATTN_STAGE(0, 0);
  __syncthreads();
  int cur = 0;
  for (int kts = 0; kts < 8; ++kts) {
    if (kts + 1 < 8) ATTN_STAGE(cur ^ 1, kts + 1);

#pragma unroll
    for (int half = 0; half < 2; ++half) {
      f32x16 sacc[2] = {};
      __builtin_amdgcn_s_setprio(1);
#pragma unroll
      for (int ds = 0; ds < 4; ds++) {
#pragma unroll
        for (int kg = 0; kg < 2; kg++) {
          int krow = half * 64 + kg * 32 + l31;
          int eoff = krow * 64 + (((ds * 2 + hi) ^ (krow & 7)) * 8);
          bf16x8 kf = *(const bf16x8*)&Ks[cur][eoff];
          sacc[kg] = __builtin_amdgcn_mfma_f32_32x32x16_bf16(
              kf, qf[ds], sacc[kg], 0, 0, 0);
        }
      }
      __builtin_amdgcn_s_setprio(0);
#pragma unroll
      for (int kg = 0; kg < 2; kg++) {
#pragma unroll
        for (int mm = 0; mm < 4; mm++) {
          f32x4 bb = *(const f32x4*)&bias[b * 1024 + kts * 128 + half * 64 +
                                          kg * 32 + mm * 8 + hi * 4];
#pragma unroll
          for (int rr = 0; rr < 4; rr++)
            sacc[kg][mm * 4 + rr] += (2.0f * LOG2E) * bb[rr];
        }
      }
      float tm = -INFINITY;
#pragma unroll
      for (int kg = 0; kg < 2; kg++)
#pragma unroll
        for (int r = 0; r < 16; r++) tm = fmaxf(tm, sacc[kg][r]);
      tm = fmaxf(tm, __shfl_xor(tm, 32));
      // defer-max: skip O/l rescale while tile max stays within 2^8 of mrun
      if (!__all(tm <= mrun + 8.0f)) {
        float mnew = fmaxf(mrun, tm);
        float sc = exp2f(mrun - mnew);
        lrun *= sc;
#pragma unroll
        for (int dg = 0; dg < 2; dg++)
#pragma unroll
          for (int r = 0; r < 16; r++) cacc[dg][r] *= sc;
        mrun = mnew;
      }
      float rsum = 0.f;
#pragma unroll
      for (int kg = 0; kg < 2; kg++)
#pragma unroll
        for (int r = 0; r < 16; r++) {
          float p = exp2f(sacc[kg][r] - mrun);
          sacc[kg][r] = p;
          rsum += p;
        }
      rsum += __shfl_xor(rsum, 32);
      lrun += rsum;

      bf16x8 pb[4];
#pragma unroll
      for (int kg = 0; kg < 2; kg++) {
#pragma unroll
        for (int tt = 0; tt < 2; tt++) {
          uint32_t w0A, w1A, w0B, w1B;
          const int mA = 2 * tt, mB = 2 * tt + 1;
          asm("v_cvt_pk_bf16_f32 %0, %1, %2"
              : "=v"(w0A)
              : "v"(sacc[kg][4 * mA + 0]), "v"(sacc[kg][4 * mA + 1]));
          asm("v_cvt_pk_bf16_f32 %0, %1, %2"
              : "=v"(w1A)
              : "v"(sacc[kg][4 * mA + 2]), "v"(sacc[kg][4 * mA + 3]));
          asm("v_cvt_pk_bf16_f32 %0, %1, %2"
              : "=v"(w0B)
              : "v"(sacc[kg][4 * mB + 0]), "v"(sacc[kg][4 * mB + 1]));
          asm("v_cvt_pk_bf16_f32 %0, %1, %2"
              : "=v"(w1B)
              : "v"(sacc[kg][4 * mB + 2]), "v"(sacc[kg][4 * mB + 3]));
          asm("v_permlane32_swap_b32 %0, %1" : "+v"(w0A), "+v"(w0B));
          asm("v_permlane32_swap_b32 %0, %1" : "+v"(w1A), "+v"(w1B));
          union { uint32_t u[4]; bf16x8 v; } pk;
          pk.u[0] = w0A; pk.u[1] = w1A; pk.u[2] = w0B; pk.u[3] = w1B;
          pb[kg * 2 + tt] = pk.v;
        }
      }
      __builtin_amdgcn_s_setprio(1);
#pragma unroll
      for (int dg = 0; dg < 2; dg++) {
#pragma unroll
        for (int k4 = 0; k4 < 4; k4++) {
          int vrow = dg * 32 + l31;
          int s = half * 8 + k4 * 2 + hi;
          int eoff = vrow * 128 + ((s ^ ((vrow & 7) << 1)) * 8);
          bf16x8 vf = *(const bf16x8*)&Vs[cur][eoff];
          cacc[dg] = __builtin_amdgcn_mfma_f32_32x32x16_bf16(
              vf, pb[k4], cacc[dg], 0, 0, 0);
        }
      }
      __builtin_amdgcn_s_setprio(0);
    }
    __syncthreads();
    cur ^= 1;
  }

  bf16_t* T = (bf16_t*)Ks;
  {
    float inv = 1.0f / lrun;
#pragma unroll
    for (int dg = 0; dg < 2; dg++) {
#pragma unroll
      for (int m = 0; m < 4; m++) {
        bf16x4 tv;
#pragma unroll
        for (int rr = 0; rr < 4; rr++)
          tv[rr] = (bf16_t)(cacc[dg][4 * m + rr] * inv);
        int d0 = dg * 32 + m * 8 + hi * 4;
        *(bf16x4*)&T[q_local * 64 + (d0 ^ ((q_local & 7) << 3))] = tv;
      }
    }
  }
  __syncthreads();
#pragma unroll
  for (int c = t; c < 1024; c += 256) {
    int row = c >> 3, col8 = c & 7;
    bf16x8 v = *(const bf16x8*)&T[row * 64 + ((col8 * 8) ^ ((row & 7) << 3))];
    *(bf16x8*)&ctx[(size_t)(b * 1024 + qt * 128 + row) * 1024 + h * 64 +
                   col8 * 8] = v;
  }
#undef ATTN_STAGE
}

extern "C" void kernel_launch(void* const* d_in, const int* in_sizes, int n_in,
                              void* d_out, int out_size, void* d_ws,
                              size_t ws_size, hipStream_t stream) {
  const float* x = (const float*)d_in[0];    // [4,1024,1024]
  const float* y = (const float*)d_in[1];    // [2,4,1024,1024]
  const float* bias = (const float*)d_in[2]; // [4,1,1,1024]
  const float* Wq = (const float*)d_in[3];   // [1024,1024]
  const float* Wk = (const float*)d_in[4];   // [2,1024,1024]
  const float* Wv = (const float*)d_in[5];
  const float* Wo = (const float*)d_in[6];
  float* out = (float*)d_out;                // [4,1024,1024] fp32

  char* ws = (char*)d_ws;
  const size_t MB = 1024 * 1024;
  bf16_t* xb   = (bf16_t*)(ws + 0 * MB);    // 8MB
  bf16_t* yb   = (bf16_t*)(ws + 8 * MB);    // 16MB
  bf16_t* WqT  = (bf16_t*)(ws + 24 * MB);   // 2MB
  bf16_t* WkvT = (bf16_t*)(ws + 26 * MB);   // 8MB  [2048 n][2048 k]
  bf16_t* WoT  = (bf16_t*)(ws + 34 * MB);   // 2MB
  bf16_t* Qb   = (bf16_t*)(ws + 36 * MB);   // 8MB  (pre-scaled d^-.5*log2e)
  bf16_t* Kb   = (bf16_t*)(ws + 44 * MB);   // 8MB
  bf16_t* VTb  = (bf16_t*)(ws + 52 * MB);   // 8MB  [1024 d][4096 q]
  bf16_t* ctxb = (bf16_t*)(ws + 60 * MB);   // 8MB

  prep_kernel<<<12288, 256, 0, stream>>>(x, y, Wq, Wk, Wv, Wo, xb, yb, WqT,
                                         WkvT, WoT);
  // KV-proj (blocks 0..511, long, first) + Q-proj (512..767), 128^2 tiles
  qkv_kernel<<<768, 256, 0, stream>>>(xb, yb, WqT, WkvT, Qb, Kb, VTb);
  attn_kernel<<<512, 256, 0, stream>>>(Qb, Kb, VTb, bias, ctxb);
  gemm_o<<<512, 256, 0, stream>>>(ctxb, WoT, out);
}